// Round 11
// baseline (1385.388 us; speedup 1.0000x reference)
//
#include <hip/hip_runtime.h>

typedef __bf16 bf16;
typedef __bf16 bf16x2 __attribute__((ext_vector_type(2)));
typedef __bf16 bf16x4 __attribute__((ext_vector_type(4)));
typedef __bf16 bf16x8 __attribute__((ext_vector_type(8)));
typedef float  f32x4  __attribute__((ext_vector_type(4)));
typedef float  f32x16 __attribute__((ext_vector_type(16)));
typedef int    intx4  __attribute__((ext_vector_type(4)));

#define BB 4
#define SEQ 2048
#define CH 768
#define NH 12
#define HD 64
#define DFF 3072
#define MROWS (BB * SEQ)   // 8192
#define C3 (3 * CH)        // 2304
#define NBH (BB * NH)      // 48
#define RTOT (NBH * SEQ)   // 98304

__device__ inline f32x16 mfma32(bf16x8 a, bf16x8 b, f32x16 c) {
    return __builtin_amdgcn_mfma_f32_32x32x16_bf16(a, b, c, 0, 0, 0);
}
__device__ inline f32x4 mfma16(bf16x8 a, bf16x8 b, f32x4 c) {
    return __builtin_amdgcn_mfma_f32_16x16x32_bf16(a, b, c, 0, 0, 0);
}
__device__ inline void gload16(const void* g, void* l) {
    __builtin_amdgcn_global_load_lds((const __attribute__((address_space(1))) void*)g,
                                     (__attribute__((address_space(3))) void*)l, 16, 0, 0);
}
// v_permlane32_swap_b32 both-copies idiom: x=y=v; after swap x[l]=v[l|32], y[l]=v[l&31].
__device__ inline void plswap_i(int& x, int& y) {
    asm volatile("v_permlane32_swap_b32 %0, %1" : "+v"(x), "+v"(y));
}
__device__ inline void plswap_f(float& x, float& y) {
    asm volatile("v_permlane32_swap_b32 %0, %1" : "+v"(x), "+v"(y));
}
__device__ inline int bcast_lo(int v) { int x = v, y = v; plswap_i(x, y); return y; }
__device__ inline int bcast_hi(int v) { int x = v, y = v; plswap_i(x, y); return x; }

// ---------------- fp32 -> bf16 convert ----------------
__global__ void cvt_f32_bf16(const float* __restrict__ in, bf16* __restrict__ out, int n) {
    int i = (blockIdx.x * blockDim.x + threadIdx.x) * 4;
    if (i + 3 >= n) {
        for (int j = 0; j < 4 && i + j < n; ++j) out[i + j] = (bf16)in[i + j];
        return;
    }
    f32x4 v = *(const f32x4*)&in[i];
    bf16x4 o;
    #pragma unroll
    for (int j = 0; j < 4; ++j) o[j] = (bf16)v[j];
    *(bf16x4*)&out[i] = o;
}

// ------------- transpose + convert: fp32 [R,Cc] -> bf16 [Cc,R] -------------
__global__ void transpose_cvt(const float* __restrict__ in, bf16* __restrict__ out, int R, int Cc) {
    __shared__ bf16 t[32][33];
    int tx = threadIdx.x & 31, ty = threadIdx.x >> 5;
    int c0 = blockIdx.x * 32, r0 = blockIdx.y * 32;
    #pragma unroll
    for (int i = 0; i < 32; i += 8)
        t[ty + i][tx] = (bf16)in[(size_t)(r0 + ty + i) * Cc + c0 + tx];
    __syncthreads();
    #pragma unroll
    for (int i = 0; i < 32; i += 8)
        out[(size_t)(c0 + ty + i) * R + r0 + tx] = t[tx][ty + i];
}

// ------------- V transpose: qkvb [B,S,3C] (V slice) -> vt [B*H, 64, S] -------------
__global__ void transpose_v(const bf16* __restrict__ qkvb, bf16* __restrict__ vt) {
    __shared__ bf16 t[32][33];
    int tx = threadIdx.x & 31, ty = threadIdx.x >> 5;
    int n0 = blockIdx.x * 32, d0 = blockIdx.y * 32, bh = blockIdx.z;
    int b = bh / NH, h = bh - b * NH;
    #pragma unroll
    for (int i = 0; i < 32; i += 8)
        t[ty + i][tx] = qkvb[((size_t)b * SEQ + n0 + ty + i) * C3 + 2 * CH + h * HD + d0 + tx];
    __syncthreads();
    #pragma unroll
    for (int i = 0; i < 32; i += 8)
        vt[((size_t)bh * HD + d0 + ty + i) * SEQ + n0 + tx] = t[tx][ty + i];
}

// ------------- GEMM (m97 + dbuf): C[M,N] = A[M,K] * Bt[N,K]^T + bias -------------
// OMODE: 0 fp32+bias, 1 bf16+bias, 2 bf16+bias+GELU, 3 bf16 split-K partial (no bias).
template <int OMODE>
__global__ __launch_bounds__(256) void gemm_bt(const bf16* __restrict__ A,
                                               const bf16* __restrict__ Bt,
                                               const float* __restrict__ bias,
                                               void* __restrict__ Cout,
                                               int M, int N, int K, int lda) {
    __shared__ __align__(16) bf16 As[2][128][32];
    __shared__ __align__(16) bf16 Bs[2][128][32];
    const int nwg = gridDim.x * gridDim.y;
    const int orig = blockIdx.y * gridDim.x + blockIdx.x;
    const int wg = (orig & 7) * (nwg >> 3) + (orig >> 3);
    const int bm = (wg / gridDim.x) * 128, bn = (wg % gridDim.x) * 128;
    const int kbeg = blockIdx.z * K;
    const int tid = threadIdx.x;
    const int lane = tid & 63, w = tid >> 6;
    const int wr = w >> 1, wc = w & 1;
    const int lr = lane & 15, lg = lane >> 4;

    const int srow = tid >> 2, schk = (tid & 3) * 8;
    const bf16* gA0 = A + (size_t)(bm + srow) * lda + kbeg + schk;
    const bf16* gA1 = A + (size_t)(bm + 64 + srow) * lda + kbeg + schk;
    const bf16* gB0 = Bt + (size_t)(bn + srow) * lda + kbeg + schk;
    const bf16* gB1 = Bt + (size_t)(bn + 64 + srow) * lda + kbeg + schk;

    auto stage = [&](int buf, int kofs) {
        gload16(gA0 + kofs, &As[buf][srow][schk]);
        gload16(gA1 + kofs, &As[buf][64 + srow][schk]);
        gload16(gB0 + kofs, &Bs[buf][srow][schk]);
        gload16(gB1 + kofs, &Bs[buf][64 + srow][schk]);
    };

    f32x4 acc[4][4];
    #pragma unroll
    for (int i = 0; i < 4; ++i)
        #pragma unroll
        for (int j = 0; j < 4; ++j) acc[i][j] = (f32x4){0.f, 0.f, 0.f, 0.f};

    stage(0, 0);
    int cur = 0;
    for (int k0 = 0; k0 < K; k0 += 32) {
        __syncthreads();
        if (k0 + 32 < K) stage(cur ^ 1, k0 + 32);
        bf16x8 af[4], bfr[4];
        #pragma unroll
        for (int mi = 0; mi < 4; ++mi)
            af[mi] = *(const bf16x8*)&As[cur][wr * 64 + mi * 16 + lr][lg * 8];
        #pragma unroll
        for (int ni = 0; ni < 4; ++ni)
            bfr[ni] = *(const bf16x8*)&Bs[cur][wc * 64 + ni * 16 + lr][lg * 8];
        #pragma unroll
        for (int mi = 0; mi < 4; ++mi)
            #pragma unroll
            for (int ni = 0; ni < 4; ++ni)
                acc[mi][ni] = mfma16(af[mi], bfr[ni], acc[mi][ni]);
        cur ^= 1;
    }

    #pragma unroll
    for (int mi = 0; mi < 4; ++mi) {
        #pragma unroll
        for (int ni = 0; ni < 4; ++ni) {
            int col = bn + wc * 64 + ni * 16 + lr;
            float bsv = (OMODE == 3) ? 0.f : bias[col];
            #pragma unroll
            for (int r = 0; r < 4; ++r) {
                int row = bm + wr * 64 + mi * 16 + lg * 4 + r;
                float v = acc[mi][ni][r] + bsv;
                if (OMODE == 2) v = 0.5f * v * (1.0f + erff(v * 0.70710678118654752f));
                if (OMODE == 0)
                    ((float*)Cout)[(size_t)row * N + col] = v;
                else if (OMODE == 3)
                    ((bf16*)Cout)[(size_t)blockIdx.z * M * N + (size_t)row * N + col] = (bf16)v;
                else
                    ((bf16*)Cout)[(size_t)row * N + col] = (bf16)v;
            }
        }
    }
}

// ------------- flash attention, kv-split z=2, LOW-REG inner loop -------------
// Staged 64-kv tiles processed in two 32-kv halves against a SINGLE st
// accumulator (16 regs) and pa[2] (8 regs): total regs/wave ~124 -> 4 waves/SIMD
// (was 2 at ~148 with st0/st1+pa[4]). launch_bounds(256,4) enforces the budget.
#define C2F 0.18033688011112f   /* 0.125 * log2(e) */
#define THR2 11.5416f           /* 8 * log2(e) */
#define KVHALF 1024
#define NTILE 16
__global__ __launch_bounds__(256, 4) void attn_kernel(const bf16* __restrict__ qkvb,
                                                      const bf16* __restrict__ vt,
                                                      bf16* __restrict__ po,
                                                      float* __restrict__ lse) {
    __shared__ __align__(16) bf16 Kl[2][64 * 64];
    __shared__ __align__(16) bf16 Vl[2][64 * 64];
    const int tid = threadIdx.x;
    const int w = tid >> 6, lane = tid & 63;
    const int lq = lane & 31;
    const int hi = lane >> 5;
    const int lin = blockIdx.x;
    const int z = blockIdx.y;
    const int xcd = lin & 7, slot = lin >> 3;
    const int bh = xcd * 6 + (slot >> 4);
    const int qt = slot & 15;
    const int b = bh / NH, h = bh - b * NH;
    const int q0 = qt * 128 + w * 32;
    const int kvbase = z * KVHALF;

    const bf16* qbase = qkvb + (size_t)b * SEQ * C3 + h * HD;
    const bf16* kbase = qbase + CH;
    const bf16* vbase = vt + (size_t)bh * HD * SEQ;

    const int srow = tid >> 3;
    const int ksc = (tid & 7) ^ (srow & 7);
    const bf16* gk0 = kbase + (size_t)srow * C3 + ksc * 8;
    const bf16* gk1 = kbase + (size_t)(srow + 32) * C3 + ksc * 8;
    const bf16* gv0 = vbase + (size_t)srow * SEQ + ksc * 8;
    const bf16* gv1 = vbase + (size_t)(srow + 32) * SEQ + ksc * 8;
    const int ldst = tid * 8;

    bf16x8 qf[4];
    #pragma unroll
    for (int ks = 0; ks < 4; ++ks)
        qf[ks] = *(const bf16x8*)&qbase[(size_t)(q0 + lq) * C3 + ks * 16 + hi * 8];

    f32x16 o0 = {0.f}, o1 = {0.f};
    float m = -3.0e38f, l = 0.f;

    const int swz = lq & 7;

    auto stage = [&](int buf, int kv0) {
        gload16(gk0 + (size_t)kv0 * C3, &Kl[buf][ldst]);
        gload16(gk1 + (size_t)kv0 * C3, &Kl[buf][2048 + ldst]);
        gload16(gv0 + kv0, &Vl[buf][ldst]);
        gload16(gv1 + kv0, &Vl[buf][2048 + ldst]);
    };

    // Process one 32-kv half (krow = 0 or 32) of the staged tile.
    auto half = [&](const bf16* Kb, const bf16* Vb, int krow) {
        f32x16 st = {0.f};
        #pragma unroll
        for (int ks = 0; ks < 4; ++ks) {
            int c = 8 * ((2 * ks + hi) ^ swz);
            bf16x8 kfr = *(const bf16x8*)&Kb[(krow + lq) * 64 + c];
            st = mfma32(kfr, qf[ks], st);
        }
        // in-lane max over 16, one permlane for cross-half
        float t_[8];
        #pragma unroll
        for (int r = 0; r < 8; ++r) t_[r] = fmaxf(st[r], st[r + 8]);
        #pragma unroll
        for (int r = 0; r < 4; ++r) t_[r] = fmaxf(t_[r], t_[r + 4]);
        float lmax = fmaxf(fmaxf(t_[0], t_[1]), fmaxf(t_[2], t_[3]));
        float mxa = lmax, mxb = lmax;
        plswap_f(mxa, mxb);
        float m2x = fmaxf(mxa, mxb) * C2F;
        if (!__all(m2x <= m + THR2)) {
            float mn = fmaxf(m, m2x);
            float alpha = __builtin_amdgcn_exp2f(m - mn);
            m = mn;
            l *= alpha;
            #pragma unroll
            for (int r = 0; r < 16; ++r) {
                int qr = (r & 3) + 8 * (r >> 2) + 4 * hi;
                float ar = __shfl(alpha, qr);
                o0[r] *= ar;
                o1[r] *= ar;
            }
        }
        // exp2, row-sum, pack
        float p[16];
        #pragma unroll
        for (int r = 0; r < 16; ++r) p[r] = __builtin_amdgcn_exp2f(fmaf(st[r], C2F, -m));
        float s0[8];
        #pragma unroll
        for (int r = 0; r < 8; ++r) s0[r] = p[r] + p[r + 8];
        #pragma unroll
        for (int r = 0; r < 4; ++r) s0[r] += s0[r + 4];
        float ps = (s0[0] + s0[1]) + (s0[2] + s0[3]);
        float pA = ps, pB = ps;
        plswap_f(pA, pB);
        l += pA + pB;
        int a[8];
        #pragma unroll
        for (int i = 0; i < 8; ++i) {
            bf16x2 t2 = {(bf16)p[2 * i], (bf16)p[2 * i + 1]};
            a[i] = __builtin_bit_cast(int, t2);
        }
        intx4 f0 = {bcast_lo(a[0]), bcast_lo(a[1]), bcast_hi(a[2]), bcast_hi(a[3])};
        intx4 f1 = {bcast_lo(a[4]), bcast_lo(a[5]), bcast_hi(a[6]), bcast_hi(a[7])};
        bf16x8 pa0 = __builtin_bit_cast(bf16x8, f0);
        bf16x8 pa1 = __builtin_bit_cast(bf16x8, f1);
        // PV over this half's kv columns (chunks krow/16 and krow/16+1)
        #pragma unroll
        for (int c = 0; c < 2; ++c) {
            int cc = 8 * ((2 * (c + (krow >> 4) / 2) + hi) ^ swz);
            bf16x8 v0 = *(const bf16x8*)&Vb[lq * 64 + cc];
            bf16x8 v1 = *(const bf16x8*)&Vb[(32 + lq) * 64 + cc];
            bf16x8 pac = c ? pa1 : pa0;
            o0 = mfma32(pac, v0, o0);
            o1 = mfma32(pac, v1, o1);
        }
    };

    auto process = [&](const bf16* Kb, const bf16* Vb) {
        half(Kb, Vb, 0);
        half(Kb, Vb, 32);
    };

    stage(0, kvbase);
    __syncthreads();
    for (int t = 0; t < NTILE; t += 2) {
        stage(1, kvbase + (t + 1) * 64);
        process(Kl[0], Vl[0]);
        __syncthreads();
        stage(0, kvbase + (t + 2 < NTILE ? t + 2 : NTILE - 1) * 64);
        process(Kl[1], Vl[1]);
        __syncthreads();
    }

    // ---- epilogue: NORMALIZED partial O (bounded ~|V|) + per-row LSE ----
    float linv = 1.0f / l;
    const size_t rbase = (size_t)z * NBH * SEQ + (size_t)bh * SEQ + q0;
    #pragma unroll
    for (int r = 0; r < 16; ++r) {
        int qr = (r & 3) + 8 * (r >> 2) + 4 * hi;
        float lr_ = __shfl(linv, qr);
        size_t ro = (rbase + qr) * 64;
        po[ro + lq] = (bf16)(o0[r] * lr_);
        po[ro + 32 + lq] = (bf16)(o1[r] * lr_);
    }
    if (hi == 0)
        lse[rbase + lq] = m + __builtin_amdgcn_logf(l);   // v_log_f32 = log2
}

// ------------- attn combine: weights 2^(lse-max), denom in [1,2] — NaN-proof -------------
__global__ __launch_bounds__(256) void attn_combine(const bf16* __restrict__ po,
                                                    const float* __restrict__ lse,
                                                    bf16* __restrict__ attnb) {
    const int tid = threadIdx.x;
    const int row = blockIdx.x * 32 + (tid >> 3);
    const int d0 = (tid & 7) * 8;
    const int bh = row >> 11, s = row & 2047;
    const int b = bh / NH, h = bh - b * NH;
    float l0 = lse[row], l1 = lse[RTOT + row];
    float L = fmaxf(l0, l1);
    float w0 = __builtin_amdgcn_exp2f(l0 - L);
    float w1 = __builtin_amdgcn_exp2f(l1 - L);
    float wn = 1.0f / (w0 + w1);
    w0 *= wn; w1 *= wn;
    bf16x8 p0 = *(const bf16x8*)&po[(size_t)row * 64 + d0];
    bf16x8 p1 = *(const bf16x8*)&po[((size_t)RTOT + row) * 64 + d0];
    bf16x8 o;
    #pragma unroll
    for (int j = 0; j < 8; ++j)
        o[j] = (bf16)((float)p0[j] * w0 + (float)p1[j] * w1);
    *(bf16x8*)&attnb[((size_t)b * SEQ + s) * CH + h * HD + d0] = o;
}

// ------------- fused residual add + NP-way split-K reduce (bf16) + bias + LayerNorm -------------
template <int XBF16, int OUTF32, int NP>
__global__ __launch_bounds__(256) void add_ln(const void* __restrict__ xin,
                                              const bf16* __restrict__ tp,
                                              const float* __restrict__ bias,
                                              const float* __restrict__ g,
                                              const float* __restrict__ bt,
                                              void* __restrict__ yout) {
    const int row = blockIdx.x;
    const size_t base = (size_t)row * CH;
    const int tid = threadIdx.x;
    float v[3];
    #pragma unroll
    for (int k = 0; k < 3; ++k) {
        int c = tid + k * 256;
        float xv = XBF16 ? (float)((const bf16*)xin)[base + c]
                         : ((const float*)xin)[base + c];
        float acc = xv + bias[c];
        #pragma unroll
        for (int z = 0; z < NP; ++z)
            acc += (float)tp[(size_t)z * MROWS * CH + base + c];
        v[k] = acc;
    }
    __shared__ float red[4];
    float s = v[0] + v[1] + v[2];
    #pragma unroll
    for (int off = 32; off >= 1; off >>= 1) s += __shfl_down(s, off);
    if ((tid & 63) == 0) red[tid >> 6] = s;
    __syncthreads();
    float mean = (red[0] + red[1] + red[2] + red[3]) * (1.0f / 768.0f);
    float q = 0.f;
    #pragma unroll
    for (int k = 0; k < 3; ++k) {
        float d = v[k] - mean;
        q += d * d;
    }
    __syncthreads();
    #pragma unroll
    for (int off = 32; off >= 1; off >>= 1) q += __shfl_down(q, off);
    if ((tid & 63) == 0) red[tid >> 6] = q;
    __syncthreads();
    float var = (red[0] + red[1] + red[2] + red[3]) * (1.0f / 768.0f);
    float rstd = rsqrtf(var + 1e-5f);
    #pragma unroll
    for (int k = 0; k < 3; ++k) {
        int c = tid + k * 256;
        float out = (v[k] - mean) * rstd * g[c] + bt[c];
        if (OUTF32) ((float*)yout)[base + c] = out;
        else        ((bf16*)yout)[base + c] = (bf16)out;
    }
}

extern "C" void kernel_launch(void* const* d_in, const int* in_sizes, int n_in,
                              void* d_out, int out_size, void* d_ws, size_t ws_size,
                              hipStream_t stream) {
    const float* x    = (const float*)d_in[0];
    const float* Wqkv = (const float*)d_in[1];
    const float* bqkv = (const float*)d_in[2];
    const float* Wproj= (const float*)d_in[3];
    const float* bproj= (const float*)d_in[4];
    const float* g1   = (const float*)d_in[5];
    const float* b1   = (const float*)d_in[6];
    const float* g2   = (const float*)d_in[7];
    const float* b2   = (const float*)d_in[8];
    const float* Wfc1 = (const float*)d_in[9];
    const float* bfc1 = (const float*)d_in[10];
    const float* Wfc2 = (const float*)d_in[11];
    const float* bfc2 = (const float*)d_in[12];

    char* ws = (char*)d_ws;
    size_t off = 0;
    auto alloc = [&](size_t bytes) -> void* {
        void* p = ws + off;
        off += (bytes + 255) & ~(size_t)255;
        return p;
    };

    bf16* xb     = (bf16*)alloc((size_t)MROWS * CH * 2);
    bf16* WqkvT  = (bf16*)alloc((size_t)C3 * CH * 2);
    bf16* WprojT = (bf16*)alloc((size_t)CH * CH * 2);
    bf16* Wfc1T  = (bf16*)alloc((size_t)DFF * CH * 2);
    bf16* Wfc2T  = (bf16*)alloc((size_t)CH * DFF * 2);
    bf16* qkvb   = (bf16*)alloc((size_t)MROWS * C3 * 2);
    bf16* vtb    = (bf16*)alloc((size_t)NBH * HD * SEQ * 2);
    bf16* attnb  = (bf16*)alloc((size_t)MROWS * CH * 2);
    bf16* tmpP   = (bf16*)alloc((size_t)4 * MROWS * CH * 2);   // split-K partials / attn po alias
    bf16* y1b    = (bf16*)alloc((size_t)MROWS * CH * 2);
    bf16* hb     = (bf16*)alloc((size_t)MROWS * DFF * 2);
    float* lsebuf= (float*)alloc((size_t)2 * RTOT * 4);
    bf16* po = tmpP;   // attn partials alias tmpP (dead until proj)

    cvt_f32_bf16<<<(MROWS * CH / 4 + 255) / 256, 256, 0, stream>>>(x, xb, MROWS * CH);
    transpose_cvt<<<dim3(C3 / 32, CH / 32), 256, 0, stream>>>(Wqkv, WqkvT, CH, C3);
    transpose_cvt<<<dim3(CH / 32, CH / 32), 256, 0, stream>>>(Wproj, WprojT, CH, CH);
    transpose_cvt<<<dim3(DFF / 32, CH / 32), 256, 0, stream>>>(Wfc1, Wfc1T, CH, DFF);
    transpose_cvt<<<dim3(CH / 32, DFF / 32), 256, 0, stream>>>(Wfc2, Wfc2T, DFF, CH);
    // qkv = x @ Wqkv + bqkv (bf16)
    gemm_bt<1><<<dim3(C3 / 128, MROWS / 128), 256, 0, stream>>>(xb, WqkvT, bqkv, qkvb, MROWS, C3, CH, CH);
    transpose_v<<<dim3(SEQ / 32, HD / 32, NBH), 256, 0, stream>>>(qkvb, vtb);
    // attention: kv-split z=2 (normalized bf16 partials + lse), then combine
    attn_kernel<<<dim3(768, 2), 256, 0, stream>>>(qkvb, vtb, po, lsebuf);
    attn_combine<<<RTOT / 32, 256, 0, stream>>>(po, lsebuf, attnb);
    // proj: split-K=2, bf16 partials (reuses tmpP after combine)
    gemm_bt<3><<<dim3(CH / 128, MROWS / 128, 2), 256, 0, stream>>>(attnb, WprojT, nullptr, tmpP, MROWS, CH, CH / 2, CH);
    // LN1: y1b = LN(x + p0 + p1 + bproj)
    add_ln<0, 0, 2><<<MROWS, 256, 0, stream>>>(x, tmpP, bproj, g1, b1, y1b);
    // fc1 + GELU (bf16)
    gemm_bt<2><<<dim3(DFF / 128, MROWS / 128), 256, 0, stream>>>(y1b, Wfc1T, bfc1, hb, MROWS, DFF, CH, CH);
    // fc2: split-K=2
    gemm_bt<3><<<dim3(CH / 128, MROWS / 128, 2), 256, 0, stream>>>(hb, Wfc2T, nullptr, tmpP, MROWS, CH, DFF / 2, DFF);
    // LN2 -> d_out (fp32), residual = y1b (bf16)
    add_ln<1, 1, 2><<<MROWS, 256, 0, stream>>>(y1b, tmpP, bfc2, g2, b2, (float*)d_out);
}

// Round 12
// 309.974 us; speedup vs baseline: 4.4694x; 4.4694x over previous
//
#include <hip/hip_runtime.h>

typedef __bf16 bf16;
typedef __bf16 bf16x2 __attribute__((ext_vector_type(2)));
typedef __bf16 bf16x4 __attribute__((ext_vector_type(4)));
typedef __bf16 bf16x8 __attribute__((ext_vector_type(8)));
typedef float  f32x4  __attribute__((ext_vector_type(4)));
typedef float  f32x16 __attribute__((ext_vector_type(16)));
typedef int    intx4  __attribute__((ext_vector_type(4)));

#define BB 4
#define SEQ 2048
#define CH 768
#define NH 12
#define HD 64
#define DFF 3072
#define MROWS (BB * SEQ)   // 8192
#define C3 (3 * CH)        // 2304
#define NBH (BB * NH)      // 48

__device__ inline f32x16 mfma32(bf16x8 a, bf16x8 b, f32x16 c) {
    return __builtin_amdgcn_mfma_f32_32x32x16_bf16(a, b, c, 0, 0, 0);
}
__device__ inline f32x4 mfma16(bf16x8 a, bf16x8 b, f32x4 c) {
    return __builtin_amdgcn_mfma_f32_16x16x32_bf16(a, b, c, 0, 0, 0);
}
__device__ inline void gload16(const void* g, void* l) {
    __builtin_amdgcn_global_load_lds((const __attribute__((address_space(1))) void*)g,
                                     (__attribute__((address_space(3))) void*)l, 16, 0, 0);
}
// v_permlane32_swap_b32 both-copies idiom: x=y=v; after swap x[l]=v[l|32], y[l]=v[l&31].
__device__ inline void plswap_i(int& x, int& y) {
    asm volatile("v_permlane32_swap_b32 %0, %1" : "+v"(x), "+v"(y));
}
__device__ inline void plswap_f(float& x, float& y) {
    asm volatile("v_permlane32_swap_b32 %0, %1" : "+v"(x), "+v"(y));
}
__device__ inline int bcast_lo(int v) { int x = v, y = v; plswap_i(x, y); return y; }
__device__ inline int bcast_hi(int v) { int x = v, y = v; plswap_i(x, y); return x; }

// ------------- fused prologue: x->bf16 cvt + 4 weight transpose-cvts -------------
// blocks [0,6144): cvt x (1024 elems/block)
// [6144,7872): WqkvT  [7872,8448): WprojT  [8448,10752): Wfc1T  [10752,13056): Wfc2T
__global__ __launch_bounds__(256) void prep_kernel(
    const float* __restrict__ x, bf16* __restrict__ xb,
    const float* __restrict__ Wqkv, bf16* __restrict__ WqkvT,
    const float* __restrict__ Wproj, bf16* __restrict__ WprojT,
    const float* __restrict__ Wfc1, bf16* __restrict__ Wfc1T,
    const float* __restrict__ Wfc2, bf16* __restrict__ Wfc2T) {
    __shared__ bf16 t[32][33];
    int bid = blockIdx.x;
    if (bid < 6144) {
        int i = (bid * 256 + threadIdx.x) * 4;
        f32x4 v = *(const f32x4*)&x[i];
        bf16x4 o;
        #pragma unroll
        for (int j = 0; j < 4; ++j) o[j] = (bf16)v[j];
        *(bf16x4*)&xb[i] = o;
        return;
    }
    bid -= 6144;
    const float* src;
    bf16* dst;
    int R, Cc, wT;
    if (bid < 1728)      { src = Wqkv;  dst = WqkvT;  R = CH;  Cc = C3;  wT = 72; }
    else if (bid < 2304) { bid -= 1728; src = Wproj; dst = WprojT; R = CH;  Cc = CH;  wT = 24; }
    else if (bid < 4608) { bid -= 2304; src = Wfc1;  dst = Wfc1T;  R = CH;  Cc = DFF; wT = 96; }
    else                 { bid -= 4608; src = Wfc2;  dst = Wfc2T;  R = DFF; Cc = CH;  wT = 24; }
    int tx = threadIdx.x & 31, ty = threadIdx.x >> 5;
    int c0 = (bid % wT) * 32, r0 = (bid / wT) * 32;
    #pragma unroll
    for (int i = 0; i < 32; i += 8)
        t[ty + i][tx] = (bf16)src[(size_t)(r0 + ty + i) * Cc + c0 + tx];
    __syncthreads();
    #pragma unroll
    for (int i = 0; i < 32; i += 8)
        dst[(size_t)(c0 + ty + i) * R + r0 + tx] = t[tx][ty + i];
}

// ------------- V transpose: qkvb [B,S,3C] (V slice) -> vt [B*H, 64, S] -------------
__global__ void transpose_v(const bf16* __restrict__ qkvb, bf16* __restrict__ vt) {
    __shared__ bf16 t[32][33];
    int tx = threadIdx.x & 31, ty = threadIdx.x >> 5;
    int n0 = blockIdx.x * 32, d0 = blockIdx.y * 32, bh = blockIdx.z;
    int b = bh / NH, h = bh - b * NH;
    #pragma unroll
    for (int i = 0; i < 32; i += 8)
        t[ty + i][tx] = qkvb[((size_t)b * SEQ + n0 + ty + i) * C3 + 2 * CH + h * HD + d0 + tx];
    __syncthreads();
    #pragma unroll
    for (int i = 0; i < 32; i += 8)
        vt[((size_t)bh * HD + d0 + ty + i) * SEQ + n0 + tx] = t[tx][ty + i];
}

// ------------- GEMM (m97 + dbuf): C[M,N] = A[M,K] * Bt[N,K]^T + bias -------------
// OMODE: 0 fp32+bias, 1 bf16+bias, 2 bf16+bias+GELU, 3 bf16 split-K partial (no bias).
template <int OMODE>
__global__ __launch_bounds__(256) void gemm_bt(const bf16* __restrict__ A,
                                               const bf16* __restrict__ Bt,
                                               const float* __restrict__ bias,
                                               void* __restrict__ Cout,
                                               int M, int N, int K, int lda) {
    __shared__ __align__(16) bf16 As[2][128][32];
    __shared__ __align__(16) bf16 Bs[2][128][32];
    const int nwg = gridDim.x * gridDim.y;
    const int orig = blockIdx.y * gridDim.x + blockIdx.x;
    const int wg = (orig & 7) * (nwg >> 3) + (orig >> 3);
    const int bm = (wg / gridDim.x) * 128, bn = (wg % gridDim.x) * 128;
    const int kbeg = blockIdx.z * K;
    const int tid = threadIdx.x;
    const int lane = tid & 63, w = tid >> 6;
    const int wr = w >> 1, wc = w & 1;
    const int lr = lane & 15, lg = lane >> 4;

    const int srow = tid >> 2, schk = (tid & 3) * 8;
    const bf16* gA0 = A + (size_t)(bm + srow) * lda + kbeg + schk;
    const bf16* gA1 = A + (size_t)(bm + 64 + srow) * lda + kbeg + schk;
    const bf16* gB0 = Bt + (size_t)(bn + srow) * lda + kbeg + schk;
    const bf16* gB1 = Bt + (size_t)(bn + 64 + srow) * lda + kbeg + schk;

    auto stage = [&](int buf, int kofs) {
        gload16(gA0 + kofs, &As[buf][srow][schk]);
        gload16(gA1 + kofs, &As[buf][64 + srow][schk]);
        gload16(gB0 + kofs, &Bs[buf][srow][schk]);
        gload16(gB1 + kofs, &Bs[buf][64 + srow][schk]);
    };

    f32x4 acc[4][4];
    #pragma unroll
    for (int i = 0; i < 4; ++i)
        #pragma unroll
        for (int j = 0; j < 4; ++j) acc[i][j] = (f32x4){0.f, 0.f, 0.f, 0.f};

    stage(0, 0);
    int cur = 0;
    for (int k0 = 0; k0 < K; k0 += 32) {
        __syncthreads();
        if (k0 + 32 < K) stage(cur ^ 1, k0 + 32);
        bf16x8 af[4], bfr[4];
        #pragma unroll
        for (int mi = 0; mi < 4; ++mi)
            af[mi] = *(const bf16x8*)&As[cur][wr * 64 + mi * 16 + lr][lg * 8];
        #pragma unroll
        for (int ni = 0; ni < 4; ++ni)
            bfr[ni] = *(const bf16x8*)&Bs[cur][wc * 64 + ni * 16 + lr][lg * 8];
        #pragma unroll
        for (int mi = 0; mi < 4; ++mi)
            #pragma unroll
            for (int ni = 0; ni < 4; ++ni)
                acc[mi][ni] = mfma16(af[mi], bfr[ni], acc[mi][ni]);
        cur ^= 1;
    }

    #pragma unroll
    for (int mi = 0; mi < 4; ++mi) {
        #pragma unroll
        for (int ni = 0; ni < 4; ++ni) {
            int col = bn + wc * 64 + ni * 16 + lr;
            float bsv = (OMODE == 3) ? 0.f : bias[col];
            #pragma unroll
            for (int r = 0; r < 4; ++r) {
                int row = bm + wr * 64 + mi * 16 + lg * 4 + r;
                float v = acc[mi][ni][r] + bsv;
                if (OMODE == 2) v = 0.5f * v * (1.0f + erff(v * 0.70710678118654752f));
                if (OMODE == 0)
                    ((float*)Cout)[(size_t)row * N + col] = v;
                else if (OMODE == 3)
                    ((bf16*)Cout)[(size_t)blockIdx.z * M * N + (size_t)row * N + col] = (bf16)v;
                else
                    ((bf16*)Cout)[(size_t)row * N + col] = (bf16)v;
            }
        }
    }
}

// ------------- flash attention (r7 body + 4-buffer staging, 1 barrier / 2 tiles) -------------
#define C2F 0.18033688011112f   /* 0.125 * log2(e) */
#define THR2 11.5416f           /* 8 * log2(e) */
__global__ __launch_bounds__(256, 3) void attn_kernel(const bf16* __restrict__ qkvb,
                                                      const bf16* __restrict__ vt,
                                                      bf16* __restrict__ outb) {
    __shared__ __align__(16) bf16 Kl[4][64 * 64];   // 32 KB
    __shared__ __align__(16) bf16 Vl[4][64 * 64];   // 32 KB
    const int tid = threadIdx.x;
    const int w = tid >> 6, lane = tid & 63;
    const int lq = lane & 31;
    const int hi = lane >> 5;
    const int lin = blockIdx.x;
    const int xcd = lin & 7, slot = lin >> 3;
    const int bh = xcd * 6 + (slot >> 4);
    const int qt = slot & 15;
    const int b = bh / NH, h = bh - b * NH;
    const int q0 = qt * 128 + w * 32;

    const bf16* qbase = qkvb + (size_t)b * SEQ * C3 + h * HD;
    const bf16* kbase = qbase + CH;
    const bf16* vbase = vt + (size_t)bh * HD * SEQ;

    const int srow = tid >> 3;
    const int ksc = (tid & 7) ^ (srow & 7);
    const bf16* gk0 = kbase + (size_t)srow * C3 + ksc * 8;
    const bf16* gk1 = kbase + (size_t)(srow + 32) * C3 + ksc * 8;
    const bf16* gv0 = vbase + (size_t)srow * SEQ + ksc * 8;
    const bf16* gv1 = vbase + (size_t)(srow + 32) * SEQ + ksc * 8;
    const int ldst = tid * 8;

    bf16x8 qf[4];
    #pragma unroll
    for (int ks = 0; ks < 4; ++ks)
        qf[ks] = *(const bf16x8*)&qbase[(size_t)(q0 + lq) * C3 + ks * 16 + hi * 8];

    f32x16 o0 = {0.f}, o1 = {0.f};
    float m = -3.0e38f, l = 0.f;

    const int swz = lq & 7;

    auto stage = [&](int buf, int kv0) {
        gload16(gk0 + (size_t)kv0 * C3, &Kl[buf][ldst]);
        gload16(gk1 + (size_t)kv0 * C3, &Kl[buf][2048 + ldst]);
        gload16(gv0 + kv0, &Vl[buf][ldst]);
        gload16(gv1 + kv0, &Vl[buf][2048 + ldst]);
    };

    auto process = [&](const bf16* Kb, const bf16* Vb) {
        f32x16 st0 = {0.f}, st1 = {0.f};
        #pragma unroll
        for (int ks = 0; ks < 4; ++ks) {
            int c = 8 * ((2 * ks + hi) ^ swz);
            bf16x8 k0 = *(const bf16x8*)&Kb[lq * 64 + c];
            bf16x8 k1 = *(const bf16x8*)&Kb[(32 + lq) * 64 + c];
            st0 = mfma32(k0, qf[ks], st0);
            st1 = mfma32(k1, qf[ks], st1);
        }
        float t_[8];
        #pragma unroll
        for (int r = 0; r < 8; ++r)
            t_[r] = fmaxf(fmaxf(st0[r], st0[r + 8]), fmaxf(st1[r], st1[r + 8]));
        #pragma unroll
        for (int r = 0; r < 4; ++r) t_[r] = fmaxf(t_[r], t_[r + 4]);
        float lmax = fmaxf(fmaxf(t_[0], t_[1]), fmaxf(t_[2], t_[3]));
        float mxa = lmax, mxb = lmax;
        plswap_f(mxa, mxb);
        float m2x = fmaxf(mxa, mxb) * C2F;
        if (!__all(m2x <= m + THR2)) {
            float mn = fmaxf(m, m2x);
            float alpha = __builtin_amdgcn_exp2f(m - mn);
            m = mn;
            l *= alpha;
            #pragma unroll
            for (int r = 0; r < 16; ++r) {
                int qr = (r & 3) + 8 * (r >> 2) + 4 * hi;
                float ar = __shfl(alpha, qr);
                o0[r] *= ar;
                o1[r] *= ar;
            }
        }
        bf16x8 pa[4];
        float ps0, ps1;
        {
            float p[16];
            #pragma unroll
            for (int r = 0; r < 16; ++r) p[r] = __builtin_amdgcn_exp2f(fmaf(st0[r], C2F, -m));
            float s0[8];
            #pragma unroll
            for (int r = 0; r < 8; ++r) s0[r] = p[r] + p[r + 8];
            #pragma unroll
            for (int r = 0; r < 4; ++r) s0[r] += s0[r + 4];
            ps0 = (s0[0] + s0[1]) + (s0[2] + s0[3]);
            int a[8];
            #pragma unroll
            for (int i = 0; i < 8; ++i) {
                bf16x2 t2 = {(bf16)p[2 * i], (bf16)p[2 * i + 1]};
                a[i] = __builtin_bit_cast(int, t2);
            }
            intx4 f0 = {bcast_lo(a[0]), bcast_lo(a[1]), bcast_hi(a[2]), bcast_hi(a[3])};
            intx4 f1 = {bcast_lo(a[4]), bcast_lo(a[5]), bcast_hi(a[6]), bcast_hi(a[7])};
            pa[0] = __builtin_bit_cast(bf16x8, f0);
            pa[1] = __builtin_bit_cast(bf16x8, f1);
        }
        {
            float p[16];
            #pragma unroll
            for (int r = 0; r < 16; ++r) p[r] = __builtin_amdgcn_exp2f(fmaf(st1[r], C2F, -m));
            float s0[8];
            #pragma unroll
            for (int r = 0; r < 8; ++r) s0[r] = p[r] + p[r + 8];
            #pragma unroll
            for (int r = 0; r < 4; ++r) s0[r] += s0[r + 4];
            ps1 = (s0[0] + s0[1]) + (s0[2] + s0[3]);
            int a[8];
            #pragma unroll
            for (int i = 0; i < 8; ++i) {
                bf16x2 t2 = {(bf16)p[2 * i], (bf16)p[2 * i + 1]};
                a[i] = __builtin_bit_cast(int, t2);
            }
            intx4 f0 = {bcast_lo(a[0]), bcast_lo(a[1]), bcast_hi(a[2]), bcast_hi(a[3])};
            intx4 f1 = {bcast_lo(a[4]), bcast_lo(a[5]), bcast_hi(a[6]), bcast_hi(a[7])};
            pa[2] = __builtin_bit_cast(bf16x8, f0);
            pa[3] = __builtin_bit_cast(bf16x8, f1);
        }
        float ps = ps0 + ps1;
        float pA = ps, pB = ps;
        plswap_f(pA, pB);
        l += pA + pB;
        #pragma unroll
        for (int c = 0; c < 4; ++c) {
            int cc = 8 * ((2 * c + hi) ^ swz);
            bf16x8 v0 = *(const bf16x8*)&Vb[lq * 64 + cc];
            bf16x8 v1 = *(const bf16x8*)&Vb[(32 + lq) * 64 + cc];
            o0 = mfma32(pa[c], v0, o0);
            o1 = mfma32(pa[c], v1, o1);
        }
    };

    // 4-buffer pipeline: stage 2 tiles, then per iteration {stage next 2,
    // process 2, ONE barrier}. Barrier count 33 -> 17; each drain covers 2 tiles.
    stage(0, 0);
    stage(1, 64);
    __syncthreads();
    for (int t = 0; t < 32; t += 2) {
        if (t + 2 < 32) {
            stage((t + 2) & 3, (t + 2) * 64);
            stage((t + 3) & 3, (t + 3) * 64);
        }
        process(Kl[t & 3], Vl[t & 3]);
        process(Kl[(t + 1) & 3], Vl[(t + 1) & 3]);
        __syncthreads();
    }

    float linv = 1.0f / l;
    const size_t obase = (size_t)b * SEQ * CH + h * HD;
    #pragma unroll
    for (int r = 0; r < 16; ++r) {
        int qr = (r & 3) + 8 * (r >> 2) + 4 * hi;
        float lr_ = __shfl(linv, qr);
        size_t rowo = obase + (size_t)(q0 + qr) * CH;
        outb[rowo + lq] = (bf16)(o0[r] * lr_);
        outb[rowo + 32 + lq] = (bf16)(o1[r] * lr_);
    }
}

// ------------- fused residual add + NP-way split-K reduce (bf16) + bias + LayerNorm -------------
template <int XBF16, int OUTF32, int NP>
__global__ __launch_bounds__(256) void add_ln(const void* __restrict__ xin,
                                              const bf16* __restrict__ tp,
                                              const float* __restrict__ bias,
                                              const float* __restrict__ g,
                                              const float* __restrict__ bt,
                                              void* __restrict__ yout) {
    const int row = blockIdx.x;
    const size_t base = (size_t)row * CH;
    const int tid = threadIdx.x;
    float v[3];
    #pragma unroll
    for (int k = 0; k < 3; ++k) {
        int c = tid + k * 256;
        float xv = XBF16 ? (float)((const bf16*)xin)[base + c]
                         : ((const float*)xin)[base + c];
        float acc = xv + bias[c];
        #pragma unroll
        for (int z = 0; z < NP; ++z)
            acc += (float)tp[(size_t)z * MROWS * CH + base + c];
        v[k] = acc;
    }
    __shared__ float red[4];
    float s = v[0] + v[1] + v[2];
    #pragma unroll
    for (int off = 32; off >= 1; off >>= 1) s += __shfl_down(s, off);
    if ((tid & 63) == 0) red[tid >> 6] = s;
    __syncthreads();
    float mean = (red[0] + red[1] + red[2] + red[3]) * (1.0f / 768.0f);
    float q = 0.f;
    #pragma unroll
    for (int k = 0; k < 3; ++k) {
        float d = v[k] - mean;
        q += d * d;
    }
    __syncthreads();
    #pragma unroll
    for (int off = 32; off >= 1; off >>= 1) q += __shfl_down(q, off);
    if ((tid & 63) == 0) red[tid >> 6] = q;
    __syncthreads();
    float var = (red[0] + red[1] + red[2] + red[3]) * (1.0f / 768.0f);
    float rstd = rsqrtf(var + 1e-5f);
    #pragma unroll
    for (int k = 0; k < 3; ++k) {
        int c = tid + k * 256;
        float out = (v[k] - mean) * rstd * g[c] + bt[c];
        if (OUTF32) ((float*)yout)[base + c] = out;
        else        ((bf16*)yout)[base + c] = (bf16)out;
    }
}

extern "C" void kernel_launch(void* const* d_in, const int* in_sizes, int n_in,
                              void* d_out, int out_size, void* d_ws, size_t ws_size,
                              hipStream_t stream) {
    const float* x    = (const float*)d_in[0];
    const float* Wqkv = (const float*)d_in[1];
    const float* bqkv = (const float*)d_in[2];
    const float* Wproj= (const float*)d_in[3];
    const float* bproj= (const float*)d_in[4];
    const float* g1   = (const float*)d_in[5];
    const float* b1   = (const float*)d_in[6];
    const float* g2   = (const float*)d_in[7];
    const float* b2   = (const float*)d_in[8];
    const float* Wfc1 = (const float*)d_in[9];
    const float* bfc1 = (const float*)d_in[10];
    const float* Wfc2 = (const float*)d_in[11];
    const float* bfc2 = (const float*)d_in[12];

    char* ws = (char*)d_ws;
    size_t off = 0;
    auto alloc = [&](size_t bytes) -> void* {
        void* p = ws + off;
        off += (bytes + 255) & ~(size_t)255;
        return p;
    };

    bf16* xb     = (bf16*)alloc((size_t)MROWS * CH * 2);
    bf16* WqkvT  = (bf16*)alloc((size_t)C3 * CH * 2);
    bf16* WprojT = (bf16*)alloc((size_t)CH * CH * 2);
    bf16* Wfc1T  = (bf16*)alloc((size_t)DFF * CH * 2);
    bf16* Wfc2T  = (bf16*)alloc((size_t)CH * DFF * 2);
    bf16* qkvb   = (bf16*)alloc((size_t)MROWS * C3 * 2);
    bf16* vtb    = (bf16*)alloc((size_t)NBH * HD * SEQ * 2);
    bf16* attnb  = (bf16*)alloc((size_t)MROWS * CH * 2);
    bf16* tmpP   = (bf16*)alloc((size_t)2 * MROWS * CH * 2);   // split-K=2 partials
    bf16* y1b    = (bf16*)alloc((size_t)MROWS * CH * 2);
    bf16* hb     = (bf16*)alloc((size_t)MROWS * DFF * 2);

    // fused prologue (cvt + 4 transposes)
    prep_kernel<<<13056, 256, 0, stream>>>(x, xb, Wqkv, WqkvT, Wproj, WprojT,
                                           Wfc1, Wfc1T, Wfc2, Wfc2T);
    // qkv = x @ Wqkv + bqkv (bf16)
    gemm_bt<1><<<dim3(C3 / 128, MROWS / 128), 256, 0, stream>>>(xb, WqkvT, bqkv, qkvb, MROWS, C3, CH, CH);
    transpose_v<<<dim3(SEQ / 32, HD / 32, NBH), 256, 0, stream>>>(qkvb, vtb);
    // attention (single-pass, 4-buffer staging)
    attn_kernel<<<768, 256, 0, stream>>>(qkvb, vtb, attnb);
    // proj: split-K=2, bf16 partials
    gemm_bt<3><<<dim3(CH / 128, MROWS / 128, 2), 256, 0, stream>>>(attnb, WprojT, nullptr, tmpP, MROWS, CH, CH / 2, CH);
    // LN1: y1b = LN(x + p0 + p1 + bproj)
    add_ln<0, 0, 2><<<MROWS, 256, 0, stream>>>(x, tmpP, bproj, g1, b1, y1b);
    // fc1 + GELU (bf16)
    gemm_bt<2><<<dim3(DFF / 128, MROWS / 128), 256, 0, stream>>>(y1b, Wfc1T, bfc1, hb, MROWS, DFF, CH, CH);
    // fc2: split-K=2
    gemm_bt<3><<<dim3(CH / 128, MROWS / 128, 2), 256, 0, stream>>>(hb, Wfc2T, nullptr, tmpP, MROWS, CH, DFF / 2, DFF);
    // LN2 -> d_out (fp32), residual = y1b (bf16)
    add_ln<1, 1, 2><<<MROWS, 256, 0, stream>>>(y1b, tmpP, bfc2, g2, b2, (float*)d_out);
}

// Round 13
// 294.588 us; speedup vs baseline: 4.7028x; 1.0522x over previous
//
#include <hip/hip_runtime.h>

typedef __bf16 bf16;
typedef __bf16 bf16x2 __attribute__((ext_vector_type(2)));
typedef __bf16 bf16x4 __attribute__((ext_vector_type(4)));
typedef __bf16 bf16x8 __attribute__((ext_vector_type(8)));
typedef float  f32x4  __attribute__((ext_vector_type(4)));
typedef float  f32x16 __attribute__((ext_vector_type(16)));
typedef int    intx4  __attribute__((ext_vector_type(4)));

#define BB 4
#define SEQ 2048
#define CH 768
#define NH 12
#define HD 64
#define DFF 3072
#define MROWS (BB * SEQ)   // 8192
#define C3 (3 * CH)        // 2304
#define NBH (BB * NH)      // 48

__device__ inline f32x16 mfma32(bf16x8 a, bf16x8 b, f32x16 c) {
    return __builtin_amdgcn_mfma_f32_32x32x16_bf16(a, b, c, 0, 0, 0);
}
__device__ inline f32x4 mfma16(bf16x8 a, bf16x8 b, f32x4 c) {
    return __builtin_amdgcn_mfma_f32_16x16x32_bf16(a, b, c, 0, 0, 0);
}
__device__ inline void gload16(const void* g, void* l) {
    __builtin_amdgcn_global_load_lds((const __attribute__((address_space(1))) void*)g,
                                     (__attribute__((address_space(3))) void*)l, 16, 0, 0);
}
// v_permlane32_swap_b32 both-copies idiom: x=y=v; after swap x[l]=v[l|32], y[l]=v[l&31].
__device__ inline void plswap_i(int& x, int& y) {
    asm volatile("v_permlane32_swap_b32 %0, %1" : "+v"(x), "+v"(y));
}
__device__ inline void plswap_f(float& x, float& y) {
    asm volatile("v_permlane32_swap_b32 %0, %1" : "+v"(x), "+v"(y));
}
__device__ inline int bcast_lo(int v) { int x = v, y = v; plswap_i(x, y); return y; }
__device__ inline int bcast_hi(int v) { int x = v, y = v; plswap_i(x, y); return x; }

// ------------- fused prologue: x->bf16 cvt + 4 weight transpose-cvts -------------
__global__ __launch_bounds__(256) void prep_kernel(
    const float* __restrict__ x, bf16* __restrict__ xb,
    const float* __restrict__ Wqkv, bf16* __restrict__ WqkvT,
    const float* __restrict__ Wproj, bf16* __restrict__ WprojT,
    const float* __restrict__ Wfc1, bf16* __restrict__ Wfc1T,
    const float* __restrict__ Wfc2, bf16* __restrict__ Wfc2T) {
    __shared__ bf16 t[32][33];
    int bid = blockIdx.x;
    if (bid < 6144) {
        int i = (bid * 256 + threadIdx.x) * 4;
        f32x4 v = *(const f32x4*)&x[i];
        bf16x4 o;
        #pragma unroll
        for (int j = 0; j < 4; ++j) o[j] = (bf16)v[j];
        *(bf16x4*)&xb[i] = o;
        return;
    }
    bid -= 6144;
    const float* src;
    bf16* dst;
    int R, Cc, wT;
    if (bid < 1728)      { src = Wqkv;  dst = WqkvT;  R = CH;  Cc = C3;  wT = 72; }
    else if (bid < 2304) { bid -= 1728; src = Wproj; dst = WprojT; R = CH;  Cc = CH;  wT = 24; }
    else if (bid < 4608) { bid -= 2304; src = Wfc1;  dst = Wfc1T;  R = CH;  Cc = DFF; wT = 96; }
    else                 { bid -= 4608; src = Wfc2;  dst = Wfc2T;  R = DFF; Cc = CH;  wT = 24; }
    int tx = threadIdx.x & 31, ty = threadIdx.x >> 5;
    int c0 = (bid % wT) * 32, r0 = (bid / wT) * 32;
    #pragma unroll
    for (int i = 0; i < 32; i += 8)
        t[ty + i][tx] = (bf16)src[(size_t)(r0 + ty + i) * Cc + c0 + tx];
    __syncthreads();
    #pragma unroll
    for (int i = 0; i < 32; i += 8)
        dst[(size_t)(c0 + ty + i) * R + r0 + tx] = t[tx][ty + i];
}

// ------------- V transpose: qkvb [B,S,3C] (V slice) -> vt [B*H, 64, S] -------------
__global__ void transpose_v(const bf16* __restrict__ qkvb, bf16* __restrict__ vt) {
    __shared__ bf16 t[32][33];
    int tx = threadIdx.x & 31, ty = threadIdx.x >> 5;
    int n0 = blockIdx.x * 32, d0 = blockIdx.y * 32, bh = blockIdx.z;
    int b = bh / NH, h = bh - b * NH;
    #pragma unroll
    for (int i = 0; i < 32; i += 8)
        t[ty + i][tx] = qkvb[((size_t)b * SEQ + n0 + ty + i) * C3 + 2 * CH + h * HD + d0 + tx];
    __syncthreads();
    #pragma unroll
    for (int i = 0; i < 32; i += 8)
        vt[((size_t)bh * HD + d0 + ty + i) * SEQ + n0 + tx] = t[tx][ty + i];
}

// ------------- GEMM (m97 + dbuf): C[M,N] = A[M,K] * Bt[N,K]^T + bias -------------
// OMODE: 0 fp32+bias, 1 bf16+bias, 2 bf16+bias+GELU, 3 bf16 split-K partial (no bias).
template <int OMODE>
__global__ __launch_bounds__(256) void gemm_bt(const bf16* __restrict__ A,
                                               const bf16* __restrict__ Bt,
                                               const float* __restrict__ bias,
                                               void* __restrict__ Cout,
                                               int M, int N, int K, int lda) {
    __shared__ __align__(16) bf16 As[2][128][32];
    __shared__ __align__(16) bf16 Bs[2][128][32];
    const int nwg = gridDim.x * gridDim.y;
    const int orig = blockIdx.y * gridDim.x + blockIdx.x;
    const int wg = (orig & 7) * (nwg >> 3) + (orig >> 3);
    const int bm = (wg / gridDim.x) * 128, bn = (wg % gridDim.x) * 128;
    const int kbeg = blockIdx.z * K;
    const int tid = threadIdx.x;
    const int lane = tid & 63, w = tid >> 6;
    const int wr = w >> 1, wc = w & 1;
    const int lr = lane & 15, lg = lane >> 4;

    const int srow = tid >> 2, schk = (tid & 3) * 8;
    const bf16* gA0 = A + (size_t)(bm + srow) * lda + kbeg + schk;
    const bf16* gA1 = A + (size_t)(bm + 64 + srow) * lda + kbeg + schk;
    const bf16* gB0 = Bt + (size_t)(bn + srow) * lda + kbeg + schk;
    const bf16* gB1 = Bt + (size_t)(bn + 64 + srow) * lda + kbeg + schk;

    auto stage = [&](int buf, int kofs) {
        gload16(gA0 + kofs, &As[buf][srow][schk]);
        gload16(gA1 + kofs, &As[buf][64 + srow][schk]);
        gload16(gB0 + kofs, &Bs[buf][srow][schk]);
        gload16(gB1 + kofs, &Bs[buf][64 + srow][schk]);
    };

    f32x4 acc[4][4];
    #pragma unroll
    for (int i = 0; i < 4; ++i)
        #pragma unroll
        for (int j = 0; j < 4; ++j) acc[i][j] = (f32x4){0.f, 0.f, 0.f, 0.f};

    stage(0, 0);
    int cur = 0;
    for (int k0 = 0; k0 < K; k0 += 32) {
        __syncthreads();
        if (k0 + 32 < K) stage(cur ^ 1, k0 + 32);
        bf16x8 af[4], bfr[4];
        #pragma unroll
        for (int mi = 0; mi < 4; ++mi)
            af[mi] = *(const bf16x8*)&As[cur][wr * 64 + mi * 16 + lr][lg * 8];
        #pragma unroll
        for (int ni = 0; ni < 4; ++ni)
            bfr[ni] = *(const bf16x8*)&Bs[cur][wc * 64 + ni * 16 + lr][lg * 8];
        #pragma unroll
        for (int mi = 0; mi < 4; ++mi)
            #pragma unroll
            for (int ni = 0; ni < 4; ++ni)
                acc[mi][ni] = mfma16(af[mi], bfr[ni], acc[mi][ni]);
        cur ^= 1;
    }

    #pragma unroll
    for (int mi = 0; mi < 4; ++mi) {
        #pragma unroll
        for (int ni = 0; ni < 4; ++ni) {
            int col = bn + wc * 64 + ni * 16 + lr;
            float bsv = (OMODE == 3) ? 0.f : bias[col];
            #pragma unroll
            for (int r = 0; r < 4; ++r) {
                int row = bm + wr * 64 + mi * 16 + lg * 4 + r;
                float v = acc[mi][ni][r] + bsv;
                if (OMODE == 2) v = 0.5f * v * (1.0f + erff(v * 0.70710678118654752f));
                if (OMODE == 0)
                    ((float*)Cout)[(size_t)row * N + col] = v;
                else if (OMODE == 3)
                    ((bf16*)Cout)[(size_t)blockIdx.z * M * N + (size_t)row * N + col] = (bf16)v;
                else
                    ((bf16*)Cout)[(size_t)row * N + col] = (bf16)v;
            }
        }
    }
}

// ------------- flash attention (round-7 exact): 2-buffer, KVB=64, permlane softmax -------------
#define C2F 0.18033688011112f   /* 0.125 * log2(e) */
#define THR2 11.5416f           /* 8 * log2(e) */
__global__ __launch_bounds__(256, 3) void attn_kernel(const bf16* __restrict__ qkvb,
                                                      const bf16* __restrict__ vt,
                                                      bf16* __restrict__ outb) {
    __shared__ __align__(16) bf16 Kl[2][64 * 64];
    __shared__ __align__(16) bf16 Vl[2][64 * 64];
    const int tid = threadIdx.x;
    const int w = tid >> 6, lane = tid & 63;
    const int lq = lane & 31;
    const int hi = lane >> 5;
    const int lin = blockIdx.x;
    const int xcd = lin & 7, slot = lin >> 3;
    const int bh = xcd * 6 + (slot >> 4);
    const int qt = slot & 15;
    const int b = bh / NH, h = bh - b * NH;
    const int q0 = qt * 128 + w * 32;

    const bf16* qbase = qkvb + (size_t)b * SEQ * C3 + h * HD;
    const bf16* kbase = qbase + CH;
    const bf16* vbase = vt + (size_t)bh * HD * SEQ;

    const int srow = tid >> 3;
    const int ksc = (tid & 7) ^ (srow & 7);
    const bf16* gk0 = kbase + (size_t)srow * C3 + ksc * 8;
    const bf16* gk1 = kbase + (size_t)(srow + 32) * C3 + ksc * 8;
    const bf16* gv0 = vbase + (size_t)srow * SEQ + ksc * 8;
    const bf16* gv1 = vbase + (size_t)(srow + 32) * SEQ + ksc * 8;
    const int ldst = tid * 8;

    bf16x8 qf[4];
    #pragma unroll
    for (int ks = 0; ks < 4; ++ks)
        qf[ks] = *(const bf16x8*)&qbase[(size_t)(q0 + lq) * C3 + ks * 16 + hi * 8];

    f32x16 o0 = {0.f}, o1 = {0.f};
    float m = -3.0e38f, l = 0.f;

    const int swz = lq & 7;

    auto stage = [&](int buf, int kv0) {
        gload16(gk0 + (size_t)kv0 * C3, &Kl[buf][ldst]);
        gload16(gk1 + (size_t)kv0 * C3, &Kl[buf][2048 + ldst]);
        gload16(gv0 + kv0, &Vl[buf][ldst]);
        gload16(gv1 + kv0, &Vl[buf][2048 + ldst]);
    };

    auto process = [&](const bf16* Kb, const bf16* Vb) {
        f32x16 st0 = {0.f}, st1 = {0.f};
        #pragma unroll
        for (int ks = 0; ks < 4; ++ks) {
            int c = 8 * ((2 * ks + hi) ^ swz);
            bf16x8 k0 = *(const bf16x8*)&Kb[lq * 64 + c];
            bf16x8 k1 = *(const bf16x8*)&Kb[(32 + lq) * 64 + c];
            st0 = mfma32(k0, qf[ks], st0);
            st1 = mfma32(k1, qf[ks], st1);
        }
        float t_[8];
        #pragma unroll
        for (int r = 0; r < 8; ++r)
            t_[r] = fmaxf(fmaxf(st0[r], st0[r + 8]), fmaxf(st1[r], st1[r + 8]));
        #pragma unroll
        for (int r = 0; r < 4; ++r) t_[r] = fmaxf(t_[r], t_[r + 4]);
        float lmax = fmaxf(fmaxf(t_[0], t_[1]), fmaxf(t_[2], t_[3]));
        float mxa = lmax, mxb = lmax;
        plswap_f(mxa, mxb);
        float m2x = fmaxf(mxa, mxb) * C2F;
        if (!__all(m2x <= m + THR2)) {
            float mn = fmaxf(m, m2x);
            float alpha = __builtin_amdgcn_exp2f(m - mn);
            m = mn;
            l *= alpha;
            #pragma unroll
            for (int r = 0; r < 16; ++r) {
                int qr = (r & 3) + 8 * (r >> 2) + 4 * hi;
                float ar = __shfl(alpha, qr);
                o0[r] *= ar;
                o1[r] *= ar;
            }
        }
        bf16x8 pa[4];
        float ps0, ps1;
        {
            float p[16];
            #pragma unroll
            for (int r = 0; r < 16; ++r) p[r] = __builtin_amdgcn_exp2f(fmaf(st0[r], C2F, -m));
            float s0[8];
            #pragma unroll
            for (int r = 0; r < 8; ++r) s0[r] = p[r] + p[r + 8];
            #pragma unroll
            for (int r = 0; r < 4; ++r) s0[r] += s0[r + 4];
            ps0 = (s0[0] + s0[1]) + (s0[2] + s0[3]);
            int a[8];
            #pragma unroll
            for (int i = 0; i < 8; ++i) {
                bf16x2 t2 = {(bf16)p[2 * i], (bf16)p[2 * i + 1]};
                a[i] = __builtin_bit_cast(int, t2);
            }
            intx4 f0 = {bcast_lo(a[0]), bcast_lo(a[1]), bcast_hi(a[2]), bcast_hi(a[3])};
            intx4 f1 = {bcast_lo(a[4]), bcast_lo(a[5]), bcast_hi(a[6]), bcast_hi(a[7])};
            pa[0] = __builtin_bit_cast(bf16x8, f0);
            pa[1] = __builtin_bit_cast(bf16x8, f1);
        }
        {
            float p[16];
            #pragma unroll
            for (int r = 0; r < 16; ++r) p[r] = __builtin_amdgcn_exp2f(fmaf(st1[r], C2F, -m));
            float s0[8];
            #pragma unroll
            for (int r = 0; r < 8; ++r) s0[r] = p[r] + p[r + 8];
            #pragma unroll
            for (int r = 0; r < 4; ++r) s0[r] += s0[r + 4];
            ps1 = (s0[0] + s0[1]) + (s0[2] + s0[3]);
            int a[8];
            #pragma unroll
            for (int i = 0; i < 8; ++i) {
                bf16x2 t2 = {(bf16)p[2 * i], (bf16)p[2 * i + 1]};
                a[i] = __builtin_bit_cast(int, t2);
            }
            intx4 f0 = {bcast_lo(a[0]), bcast_lo(a[1]), bcast_hi(a[2]), bcast_hi(a[3])};
            intx4 f1 = {bcast_lo(a[4]), bcast_lo(a[5]), bcast_hi(a[6]), bcast_hi(a[7])};
            pa[2] = __builtin_bit_cast(bf16x8, f0);
            pa[3] = __builtin_bit_cast(bf16x8, f1);
        }
        float ps = ps0 + ps1;
        float pA = ps, pB = ps;
        plswap_f(pA, pB);
        l += pA + pB;
        #pragma unroll
        for (int c = 0; c < 4; ++c) {
            int cc = 8 * ((2 * c + hi) ^ swz);
            bf16x8 v0 = *(const bf16x8*)&Vb[lq * 64 + cc];
            bf16x8 v1 = *(const bf16x8*)&Vb[(32 + lq) * 64 + cc];
            o0 = mfma32(pa[c], v0, o0);
            o1 = mfma32(pa[c], v1, o1);
        }
    };

    stage(0, 0);
    __syncthreads();
    for (int t = 0; t < 32; t += 2) {
        stage(1, (t + 1) * 64);
        process(Kl[0], Vl[0]);
        __syncthreads();
        stage(0, (t + 2 < 32 ? t + 2 : 31) * 64);
        process(Kl[1], Vl[1]);
        __syncthreads();
    }

    float linv = 1.0f / l;
    const size_t obase = (size_t)b * SEQ * CH + h * HD;
    #pragma unroll
    for (int r = 0; r < 16; ++r) {
        int qr = (r & 3) + 8 * (r >> 2) + 4 * hi;
        float lr_ = __shfl(linv, qr);
        size_t rowo = obase + (size_t)(q0 + qr) * CH;
        outb[rowo + lq] = (bf16)(o0[r] * lr_);
        outb[rowo + 32 + lq] = (bf16)(o1[r] * lr_);
    }
}

// ------------- fused residual add + NP-way split-K reduce (bf16) + bias + LayerNorm -------------
template <int XBF16, int OUTF32, int NP>
__global__ __launch_bounds__(256) void add_ln(const void* __restrict__ xin,
                                              const bf16* __restrict__ tp,
                                              const float* __restrict__ bias,
                                              const float* __restrict__ g,
                                              const float* __restrict__ bt,
                                              void* __restrict__ yout) {
    const int row = blockIdx.x;
    const size_t base = (size_t)row * CH;
    const int tid = threadIdx.x;
    float v[3];
    #pragma unroll
    for (int k = 0; k < 3; ++k) {
        int c = tid + k * 256;
        float xv = XBF16 ? (float)((const bf16*)xin)[base + c]
                         : ((const float*)xin)[base + c];
        float acc = xv + bias[c];
        #pragma unroll
        for (int z = 0; z < NP; ++z)
            acc += (float)tp[(size_t)z * MROWS * CH + base + c];
        v[k] = acc;
    }
    __shared__ float red[4];
    float s = v[0] + v[1] + v[2];
    #pragma unroll
    for (int off = 32; off >= 1; off >>= 1) s += __shfl_down(s, off);
    if ((tid & 63) == 0) red[tid >> 6] = s;
    __syncthreads();
    float mean = (red[0] + red[1] + red[2] + red[3]) * (1.0f / 768.0f);
    float q = 0.f;
    #pragma unroll
    for (int k = 0; k < 3; ++k) {
        float d = v[k] - mean;
        q += d * d;
    }
    __syncthreads();
    #pragma unroll
    for (int off = 32; off >= 1; off >>= 1) q += __shfl_down(q, off);
    if ((tid & 63) == 0) red[tid >> 6] = q;
    __syncthreads();
    float var = (red[0] + red[1] + red[2] + red[3]) * (1.0f / 768.0f);
    float rstd = rsqrtf(var + 1e-5f);
    #pragma unroll
    for (int k = 0; k < 3; ++k) {
        int c = tid + k * 256;
        float out = (v[k] - mean) * rstd * g[c] + bt[c];
        if (OUTF32) ((float*)yout)[base + c] = out;
        else        ((bf16*)yout)[base + c] = (bf16)out;
    }
}

extern "C" void kernel_launch(void* const* d_in, const int* in_sizes, int n_in,
                              void* d_out, int out_size, void* d_ws, size_t ws_size,
                              hipStream_t stream) {
    const float* x    = (const float*)d_in[0];
    const float* Wqkv = (const float*)d_in[1];
    const float* bqkv = (const float*)d_in[2];
    const float* Wproj= (const float*)d_in[3];
    const float* bproj= (const float*)d_in[4];
    const float* g1   = (const float*)d_in[5];
    const float* b1   = (const float*)d_in[6];
    const float* g2   = (const float*)d_in[7];
    const float* b2   = (const float*)d_in[8];
    const float* Wfc1 = (const float*)d_in[9];
    const float* bfc1 = (const float*)d_in[10];
    const float* Wfc2 = (const float*)d_in[11];
    const float* bfc2 = (const float*)d_in[12];

    char* ws = (char*)d_ws;
    size_t off = 0;
    auto alloc = [&](size_t bytes) -> void* {
        void* p = ws + off;
        off += (bytes + 255) & ~(size_t)255;
        return p;
    };

    bf16* xb     = (bf16*)alloc((size_t)MROWS * CH * 2);
    bf16* WqkvT  = (bf16*)alloc((size_t)C3 * CH * 2);
    bf16* WprojT = (bf16*)alloc((size_t)CH * CH * 2);
    bf16* Wfc1T  = (bf16*)alloc((size_t)DFF * CH * 2);
    bf16* Wfc2T  = (bf16*)alloc((size_t)CH * DFF * 2);
    bf16* qkvb   = (bf16*)alloc((size_t)MROWS * C3 * 2);
    bf16* vtb    = (bf16*)alloc((size_t)NBH * HD * SEQ * 2);
    bf16* attnb  = (bf16*)alloc((size_t)MROWS * CH * 2);
    bf16* tmpP   = (bf16*)alloc((size_t)2 * MROWS * CH * 2);   // split-K=2 partials
    bf16* y1b    = (bf16*)alloc((size_t)MROWS * CH * 2);
    bf16* hb     = (bf16*)alloc((size_t)MROWS * DFF * 2);

    // fused prologue (cvt + 4 transposes)
    prep_kernel<<<13056, 256, 0, stream>>>(x, xb, Wqkv, WqkvT, Wproj, WprojT,
                                           Wfc1, Wfc1T, Wfc2, Wfc2T);
    // qkv = x @ Wqkv + bqkv (bf16)
    gemm_bt<1><<<dim3(C3 / 128, MROWS / 128), 256, 0, stream>>>(xb, WqkvT, bqkv, qkvb, MROWS, C3, CH, CH);
    transpose_v<<<dim3(SEQ / 32, HD / 32, NBH), 256, 0, stream>>>(qkvb, vtb);
    // attention (round-7 exact single-pass)
    attn_kernel<<<768, 256, 0, stream>>>(qkvb, vtb, attnb);
    // proj: split-K=2, bf16 partials
    gemm_bt<3><<<dim3(CH / 128, MROWS / 128, 2), 256, 0, stream>>>(attnb, WprojT, nullptr, tmpP, MROWS, CH, CH / 2, CH);
    // LN1: y1b = LN(x + p0 + p1 + bproj)
    add_ln<0, 0, 2><<<MROWS, 256, 0, stream>>>(x, tmpP, bproj, g1, b1, y1b);
    // fc1 + GELU (bf16)
    gemm_bt<2><<<dim3(DFF / 128, MROWS / 128), 256, 0, stream>>>(y1b, Wfc1T, bfc1, hb, MROWS, DFF, CH, CH);
    // fc2: split-K=2
    gemm_bt<3><<<dim3(CH / 128, MROWS / 128, 2), 256, 0, stream>>>(hb, Wfc2T, nullptr, tmpP, MROWS, CH, DFF / 2, DFF);
    // LN2 -> d_out (fp32), residual = y1b (bf16)
    add_ln<1, 1, 2><<<MROWS, 256, 0, stream>>>(y1b, tmpP, bfc2, g2, b2, (float*)d_out);
}